// Round 2
// baseline (26116.550 us; speedup 1.0000x reference)
//
#include <hip/hip_runtime.h>

typedef unsigned short ushort_t;
typedef unsigned int uint_t;
typedef __attribute__((ext_vector_type(8))) short short8;
typedef __attribute__((ext_vector_type(4))) float f32x4;

// ---------------- workspace layout (bytes) ----------------
constexpr size_t OFF_WSFT = 0;                               // bf16 [512][512]   WsfT[n][k] = W_sf[k][n], k<512
constexpr size_t OFF_WAFT = OFF_WSFT + 512*512*2;            // bf16 [512][512]
constexpr size_t OFF_WAST = OFF_WAFT + 512*512*2;            // bf16 [512][1024]
constexpr size_t OFF_WSST = OFF_WAST + 512*1024*2;           // bf16 [512][1024]
constexpr size_t OFF_WO1T = OFF_WSST + 512*1024*2;           // bf16 [512][1536]
constexpr size_t OFF_XTAB = OFF_WO1T + 512*1536*2;           // bf16 [600][512]   X = skill_embed[sk]+ans_embed[a]
constexpr size_t OFF_PRO  = OFF_XTAB + 600*512*2;            // bf16 [300][512]   skill_embed
constexpr size_t OFF_GAP  = OFF_PRO  + 300*512*2;            // f32  [200][512]   time_embed @ W_sf[512:] + b_sf
constexpr size_t OFF_CAF  = OFF_GAP  + 200*512*4;            // f32  [512]        time_embed[1] @ W_af[512:] + b_af
constexpr size_t OFF_SKB  = OFF_CAF  + 512*4;                // bf16 [512][199][512] skill_buf
constexpr size_t WS_NEED  = OFF_SKB  + (size_t)512*199*512*2;

__device__ __forceinline__ ushort_t f2bf(float f) {
  union { float f; uint_t u; } v; v.f = f;
  uint_t u = v.u;
  return (ushort_t)((u + 0x7FFFu + ((u >> 16) & 1u)) >> 16);
}
__device__ __forceinline__ float bf2f(ushort_t h) {
  union { uint_t u; float f; } v; v.u = ((uint_t)h) << 16;
  return v.f;
}

// ---------------- prologue: weight transposes + tables ----------------
__global__ void rekt_prep(const float* __restrict__ skill_embed, const float* __restrict__ ans_embed,
                          const float* __restrict__ skill_state0,
                          const float* __restrict__ W_sf, const float* __restrict__ W_af,
                          const float* __restrict__ W_ss, const float* __restrict__ W_as,
                          const float* __restrict__ W_o1,
                          char* __restrict__ ws) {
  ushort_t* WsfT = (ushort_t*)(ws + OFF_WSFT);
  ushort_t* WafT = (ushort_t*)(ws + OFF_WAFT);
  ushort_t* WasT = (ushort_t*)(ws + OFF_WAST);
  ushort_t* WssT = (ushort_t*)(ws + OFF_WSST);
  ushort_t* Wo1T = (ushort_t*)(ws + OFF_WO1T);
  ushort_t* Xtab = (ushort_t*)(ws + OFF_XTAB);
  ushort_t* PROt = (ushort_t*)(ws + OFF_PRO);
  ushort_t* SKB  = (ushort_t*)(ws + OFF_SKB);

  const size_t t0 = (size_t)blockIdx.x * blockDim.x + threadIdx.x;
  const size_t st = (size_t)gridDim.x * blockDim.x;

  // coalesced READS (i = k*512+n), scattered bf16 writes
  for (size_t i = t0; i < 512*512; i += st) {
    int k = (int)(i >> 9), n = (int)(i & 511);
    ushort_t vsf = f2bf(W_sf[i]);
    ushort_t vaf = f2bf(W_af[i]);
    WsfT[(size_t)n*512 + k] = vsf;
    WafT[(size_t)n*512 + k] = vaf;
  }
  for (size_t i = t0; i < 1024*512; i += st) {
    int k = (int)(i >> 9), n = (int)(i & 511);
    WasT[(size_t)n*1024 + k] = f2bf(W_as[i]);
    WssT[(size_t)n*1024 + k] = f2bf(W_ss[i]);
  }
  for (size_t i = t0; i < 1536*512; i += st) {
    int k = (int)(i >> 9), n = (int)(i & 511);
    Wo1T[(size_t)n*1536 + k] = f2bf(W_o1[i]);
  }
  for (size_t i = t0; i < 600*512; i += st) {
    int row = (int)(i >> 9), j = (int)(i & 511);
    int a = row / 300, sk = row % 300;
    Xtab[i] = f2bf(skill_embed[(size_t)sk*512 + j] + ans_embed[(size_t)a*512 + j]);
  }
  for (size_t i = t0; i < 300*512; i += st) PROt[i] = f2bf(skill_embed[i]);
  // skill_buf slot 0 per batch = skill_state0 (only slot read before written)
  for (size_t i = t0; i < 512*512; i += st) {
    size_t b = i >> 9, n = i & 511;
    SKB[((size_t)b*199)*512 + n] = f2bf(skill_state0[n]);
  }
}

// GAP[t][n] = b_sf[n] + sum_k time_embed[t][k] * W_sf[512+k][n]   (t<200)
// block 200: CAF[n] = b_af[n] + sum_k time_embed[1][k] * W_af[512+k][n]
__global__ void rekt_gap(const float* __restrict__ time_embed,
                         const float* __restrict__ W_sf, const float* __restrict__ b_sf,
                         const float* __restrict__ W_af, const float* __restrict__ b_af,
                         char* __restrict__ ws) {
  float* GAP = (float*)(ws + OFF_GAP);
  float* CAF = (float*)(ws + OFF_CAF);
  const int n = threadIdx.x;
  __shared__ float te[512];
  if (blockIdx.x < 200) {
    const int t = blockIdx.x;
    te[n] = time_embed[(size_t)t*512 + n];
    __syncthreads();
    float acc = b_sf[n];
    for (int k = 0; k < 512; ++k) acc = fmaf(te[k], W_sf[(size_t)(512 + k)*512 + n], acc);
    GAP[(size_t)t*512 + n] = acc;
  } else {
    te[n] = time_embed[512 + n];
    __syncthreads();
    float acc = b_af[n];
    for (int k = 0; k < 512; ++k) acc = fmaf(te[k], W_af[(size_t)(512 + k)*512 + n], acc);
    CAF[n] = acc;
  }
}

// ---------------- block-local GEMM: M=16, per-wave 4 N-tiles, K=512 chunk ----------------
template<int LD>
__device__ __forceinline__ void gemm4(const short* At, const ushort_t* __restrict__ WT,
                                      int nbase, int kk0, f32x4* acc) {
  const int lane = threadIdx.x & 63;
  const int hi = lane >> 4, cc = lane & 15;
  const short* ap = At + (size_t)cc * 520 + (hi << 3);              // A row = lane&15
  const ushort_t* bp = WT + (size_t)(nbase + cc) * LD + kk0 + (hi << 3);
#pragma unroll 2
  for (int kk = 0; kk < 512; kk += 32) {
    const short8 a = *reinterpret_cast<const short8*>(ap + kk);
#pragma unroll
    for (int nf = 0; nf < 4; ++nf) {
      const short8 b = *reinterpret_cast<const short8*>(bp + (size_t)(nf * 16) * LD + kk);
      acc[nf] = __builtin_amdgcn_mfma_f32_16x16x32_bf16(a, b, acc[nf], 0, 0, 0);
    }
  }
}

// ---------------- main scan: 32 blocks x 512 threads, block owns 16 batches ----------------
__global__ __launch_bounds__(512, 1) void rekt_main(
    const int* __restrict__ next_skill, const int* __restrict__ next_ans,
    const float* __restrict__ ls_state,
    const float* __restrict__ b_o1, const float* __restrict__ w_o2,
    const float* __restrict__ b_as, const float* __restrict__ b_ss,
    const float* __restrict__ b_o2,
    float* __restrict__ d_out, char* __restrict__ ws) {

  const ushort_t* WsfT = (const ushort_t*)(ws + OFF_WSFT);
  const ushort_t* WafT = (const ushort_t*)(ws + OFF_WAFT);
  const ushort_t* WasT = (const ushort_t*)(ws + OFF_WAST);
  const ushort_t* WssT = (const ushort_t*)(ws + OFF_WSST);
  const ushort_t* Wo1T = (const ushort_t*)(ws + OFF_WO1T);
  const ushort_t* Xtab = (const ushort_t*)(ws + OFF_XTAB);
  const ushort_t* PROt = (const ushort_t*)(ws + OFF_PRO);
  const float*    GAP  = (const float*)(ws + OFF_GAP);
  const float*    CAF  = (const float*)(ws + OFF_CAF);
  ushort_t*       SKB  = (ushort_t*)(ws + OFF_SKB);

  __shared__ __align__(16) short SKgX[16 * 520];   // SKg (phase A) -> X (phase B)
  __shared__ __align__(16) short ASPRO[16 * 520];  // ASbf (persistent) -> PRO (phase B) -> new ASbf
  __shared__ __align__(16) short LAb[16 * 520];
  __shared__ __align__(16) short LSb[16 * 520];
  __shared__ int LT[16 * 300];
  __shared__ int sk_s[16], gap_s[16], xr_s[16], skrow_s[16];
  __shared__ float P_s[16];

  const int tid = threadIdx.x;
  const int lane = tid & 63, w = tid >> 6;
  const int hi = lane >> 4, cc = lane & 15;
  const int rq = hi << 2;                 // acc row base: rows rq..rq+3
  const int n0 = w << 6;                  // wave owns cols [n0, n0+64)
  const int b0 = blockIdx.x << 4;         // 16 batches per block

  int nc[4]; float bo1r[4], wo2r[4], cafr[4], basr[4], bssr[4];
#pragma unroll
  for (int nf = 0; nf < 4; ++nf) {
    nc[nf] = n0 + nf * 16 + cc;
    bo1r[nf] = b_o1[nc[nf]];
    wo2r[nf] = w_o2[nc[nf]];
    cafr[nf] = CAF[nc[nf]];
    basr[nf] = b_as[nc[nf]];
    bssr[nf] = b_ss[nc[nf]];
  }
  const float bo2 = b_o2[0];

  for (int i = tid; i < 16 * 300; i += 512) LT[i] = 0;

  // states in registers: as/la/ls [nf][q] for (row rq+q, col nc[nf])
  float as[4][4], la[4][4], ls[4][4];
#pragma unroll
  for (int nf = 0; nf < 4; ++nf)
#pragma unroll
    for (int q = 0; q < 4; ++q) as[nf][q] = ls_state[nc[nf]];

  // initial ASbf = bf16(ls_state) for all 16 rows
  for (int i = tid; i < 1024; i += 512) {
    const int r = i >> 6, c = (i & 63) << 3;
#pragma unroll
    for (int j = 0; j < 8; ++j) ASPRO[r * 520 + c + j] = (short)f2bf(ls_state[c + j]);
  }
  __syncthreads();

  for (int s = 0; s < 199; ++s) {
    // ---- indices ----
    if (tid < 16) {
      const int b = b0 + tid;
      const int sk = next_skill[b * 199 + s];
      const int tl = LT[tid * 300 + sk];
      sk_s[tid] = sk;
      gap_s[tid] = s - tl;
      xr_s[tid] = next_ans[b * 199 + s] * 300 + sk;
      skrow_s[tid] = b * 199 + tl;
      LT[tid * 300 + sk] = s;              // capture tl first, then update
      P_s[tid] = 0.f;
    }
    __syncthreads();

    // ---- stage SKg (gather 16 rows from SKB) ----
    for (int i = tid; i < 1024; i += 512) {
      const int r = i >> 6, c = (i & 63) << 3;
      *reinterpret_cast<uint4*>(SKgX + r * 520 + c) =
          *reinterpret_cast<const uint4*>(SKB + (size_t)skrow_s[r] * 512 + c);
    }
    __syncthreads();

    // ---- phase A GEMMs ----
    f32x4 a1[4] = {}, a2[4] = {};
    gemm4<512>(SKgX, WsfT, n0, 0, a1);
    gemm4<512>(ASPRO, WafT, n0, 0, a2);

    // ---- epilogue A: LS = SKg*sig(F), LA = AS*sig(G) ----
#pragma unroll
    for (int nf = 0; nf < 4; ++nf) {
#pragma unroll
      for (int q = 0; q < 4; ++q) {
        const int r = rq + q;
        const float F = a1[nf][q] + GAP[(size_t)gap_s[r] * 512 + nc[nf]];
        const float sgF = 1.f / (1.f + __expf(-F));
        const float skg = bf2f((ushort_t)SKgX[r * 520 + nc[nf]]);
        const float lsv = skg * sgF;
        ls[nf][q] = lsv;
        LSb[r * 520 + nc[nf]] = (short)f2bf(lsv);
        const float G = a2[nf][q] + cafr[nf];
        const float sgG = 1.f / (1.f + __expf(-G));
        const float lav = as[nf][q] * sgG;
        la[nf][q] = lav;
        LAb[r * 520 + nc[nf]] = (short)f2bf(lav);
      }
    }
    __syncthreads();

    // ---- stage X and PRO ----
    for (int i = tid; i < 1024; i += 512) {
      const int r = i >> 6, c = (i & 63) << 3;
      *reinterpret_cast<uint4*>(SKgX + r * 520 + c) =
          *reinterpret_cast<const uint4*>(Xtab + (size_t)xr_s[r] * 512 + c);
      *reinterpret_cast<uint4*>(ASPRO + r * 520 + c) =
          *reinterpret_cast<const uint4*>(PROt + (size_t)sk_s[r] * 512 + c);
    }
    __syncthreads();

    // ---- phase B GEMMs ----
    f32x4 hh[4] = {}, na[4] = {}, ns[4] = {};
    gemm4<1536>(LAb,   Wo1T, n0, 0,    hh);
    gemm4<1536>(LSb,   Wo1T, n0, 512,  hh);
    gemm4<1536>(ASPRO, Wo1T, n0, 1024, hh);
    gemm4<1024>(LAb,  WasT, n0, 0,   na);
    gemm4<1024>(SKgX, WasT, n0, 512, na);
    gemm4<1024>(LSb,  WssT, n0, 0,   ns);
    gemm4<1024>(SKgX, WssT, n0, 512, ns);

    // ---- h epilogue: P partial, reduce over cols ----
    float pv[4];
#pragma unroll
    for (int q = 0; q < 4; ++q) {
      float p = 0.f;
#pragma unroll
      for (int nf = 0; nf < 4; ++nf) {
        const float h = fmaxf(hh[nf][q] + bo1r[nf], 0.f);
        p = fmaf(h, wo2r[nf], p);
      }
      pv[q] = p;
    }
#pragma unroll
    for (int msk = 1; msk < 16; msk <<= 1) {
#pragma unroll
      for (int q = 0; q < 4; ++q) pv[q] += __shfl_xor(pv[q], msk, 64);
    }
    if (cc == 0) {
#pragma unroll
      for (int q = 0; q < 4; ++q) atomicAdd(&P_s[rq + q], pv[q]);
    }
    __syncthreads();   // P done; PRO reads done (safe to overwrite ASPRO)

    // ---- epilogue NA/NS: update states ----
#pragma unroll
    for (int nf = 0; nf < 4; ++nf) {
#pragma unroll
      for (int q = 0; q < 4; ++q) {
        const int r = rq + q;
        float x = na[nf][q] + basr[nf];
        x = fminf(fmaxf(x, -12.f), 12.f);
        float e = __expf(2.f * x);
        const float nav = la[nf][q] + (e - 1.f) / (e + 1.f);
        as[nf][q] = nav;
        ASPRO[r * 520 + nc[nf]] = (short)f2bf(nav);

        float y = ns[nf][q] + bssr[nf];
        y = fminf(fmaxf(y, -12.f), 12.f);
        e = __expf(2.f * y);
        const float nsv = ls[nf][q] + (e - 1.f) / (e + 1.f);
        SKB[((size_t)(b0 + r) * 199 + s) * 512 + nc[nf]] = f2bf(nsv);
      }
    }
    if (tid < 16) {
      const float v = P_s[tid] + bo2;
      d_out[(size_t)(b0 + tid) * 199 + s] = 1.f / (1.f + __expf(-v));
    }
    __syncthreads();   // ASbf/SKB visible before next step
  }
}

extern "C" void kernel_launch(void* const* d_in, const int* in_sizes, int n_in,
                              void* d_out, int out_size, void* d_ws, size_t ws_size,
                              hipStream_t stream) {
  const int*   next_skill   = (const int*)d_in[4];
  const int*   next_ans     = (const int*)d_in[5];
  const float* skill_embed  = (const float*)d_in[6];
  const float* ans_embed    = (const float*)d_in[7];
  const float* time_embed   = (const float*)d_in[8];
  const float* ls_state     = (const float*)d_in[9];
  const float* skill_state0 = (const float*)d_in[10];
  const float* W_sf = (const float*)d_in[11];
  const float* b_sf = (const float*)d_in[12];
  const float* W_af = (const float*)d_in[13];
  const float* b_af = (const float*)d_in[14];
  const float* W_ss = (const float*)d_in[15];
  const float* b_ss = (const float*)d_in[16];
  const float* W_as = (const float*)d_in[17];
  const float* b_as = (const float*)d_in[18];
  const float* W_o1 = (const float*)d_in[19];
  const float* b_o1 = (const float*)d_in[20];
  const float* W_o2 = (const float*)d_in[21];
  const float* b_o2 = (const float*)d_in[22];
  float* out = (float*)d_out;
  char*  ws  = (char*)d_ws;

  if (ws_size < WS_NEED) return;

  rekt_prep<<<dim3(1024), dim3(256), 0, stream>>>(
      skill_embed, ans_embed, skill_state0, W_sf, W_af, W_ss, W_as, W_o1, ws);
  rekt_gap<<<dim3(201), dim3(512), 0, stream>>>(time_embed, W_sf, b_sf, W_af, b_af, ws);

  rekt_main<<<dim3(32), dim3(512), 0, stream>>>(
      next_skill, next_ans, ls_state, b_o1, W_o2, b_as, b_ss, b_o2, out, ws);
}

// Round 3
// 13025.978 us; speedup vs baseline: 2.0050x; 2.0050x over previous
//
#include <hip/hip_runtime.h>

typedef unsigned short ushort_t;
typedef unsigned int uint_t;
typedef __attribute__((ext_vector_type(8))) short short8;
typedef __attribute__((ext_vector_type(4))) float f32x4;
typedef __attribute__((ext_vector_type(4))) uint_t uint4v;

// ---------------- workspace layout (bytes) ----------------
constexpr size_t OFF_WSFT = 0;                               // bf16 [512][512]  WsfT[n][k]=W_sf[k][n]
constexpr size_t OFF_WAFT = OFF_WSFT + 512*512*2;            // bf16 [512][512]
constexpr size_t OFF_WAST = OFF_WAFT + 512*512*2;            // bf16 [512][1024]
constexpr size_t OFF_WSST = OFF_WAST + 512*1024*2;           // bf16 [512][1024]
constexpr size_t OFF_WO1T = OFF_WSST + 512*1024*2;           // bf16 [512][1536]
constexpr size_t OFF_XTAB = OFF_WO1T + 512*1536*2;           // bf16 [600][512]
constexpr size_t OFF_PRO  = OFF_XTAB + 600*512*2;            // bf16 [300][512]
constexpr size_t OFF_GAP  = OFF_PRO  + 300*512*2;            // f32  [200][512]
constexpr size_t OFF_CAF  = OFF_GAP  + 200*512*4;            // f32  [512]
constexpr size_t OFF_LAG  = OFF_CAF  + 512*4;                // bf16 [16][32][512] gated last_all
constexpr size_t OFF_LSG  = OFF_LAG  + 16*32*512*2;          // bf16 [16][32][512] gated last_sk
constexpr size_t OFF_ASG  = OFF_LSG  + 16*32*512*2;          // bf16 [16][32][512] all_state
constexpr size_t OFF_BAR  = OFF_ASG  + 16*32*512*2;          // i32  [16][32] barrier counters
constexpr size_t OFF_SKB  = OFF_BAR  + 16*32*4;              // bf16 [512][199][512] skill_buf
constexpr size_t WS_NEED  = OFF_SKB  + (size_t)512*199*512*2;

__device__ __forceinline__ ushort_t f2bf(float f) {
  union { float f; uint_t u; } v; v.f = f;
  uint_t u = v.u;
  return (ushort_t)((u + 0x7FFFu + ((u >> 16) & 1u)) >> 16);
}
__device__ __forceinline__ float bf2f(ushort_t h) {
  union { uint_t u; float f; } v; v.u = ((uint_t)h) << 16;
  return v.f;
}

// ---------------- prologue ----------------
__global__ void rekt_prep(const float* __restrict__ skill_embed, const float* __restrict__ ans_embed,
                          const float* __restrict__ ls_state, const float* __restrict__ skill_state0,
                          const float* __restrict__ W_sf, const float* __restrict__ W_af,
                          const float* __restrict__ W_ss, const float* __restrict__ W_as,
                          const float* __restrict__ W_o1,
                          float* __restrict__ d_out, char* __restrict__ ws) {
  ushort_t* WsfT = (ushort_t*)(ws + OFF_WSFT);
  ushort_t* WafT = (ushort_t*)(ws + OFF_WAFT);
  ushort_t* WasT = (ushort_t*)(ws + OFF_WAST);
  ushort_t* WssT = (ushort_t*)(ws + OFF_WSST);
  ushort_t* Wo1T = (ushort_t*)(ws + OFF_WO1T);
  ushort_t* Xtab = (ushort_t*)(ws + OFF_XTAB);
  ushort_t* PROt = (ushort_t*)(ws + OFF_PRO);
  ushort_t* LAG  = (ushort_t*)(ws + OFF_LAG);
  ushort_t* ASG  = (ushort_t*)(ws + OFF_ASG);
  int*      BARp = (int*)(ws + OFF_BAR);
  ushort_t* SKB  = (ushort_t*)(ws + OFF_SKB);

  const size_t t0 = (size_t)blockIdx.x * blockDim.x + threadIdx.x;
  const size_t st = (size_t)gridDim.x * blockDim.x;

  for (size_t i = t0; i < 512*512; i += st) {
    int k = (int)(i >> 9), n = (int)(i & 511);
    WsfT[(size_t)n*512 + k] = f2bf(W_sf[i]);
    WafT[(size_t)n*512 + k] = f2bf(W_af[i]);
  }
  for (size_t i = t0; i < 1024*512; i += st) {
    int k = (int)(i >> 9), n = (int)(i & 511);
    WasT[(size_t)n*1024 + k] = f2bf(W_as[i]);
    WssT[(size_t)n*1024 + k] = f2bf(W_ss[i]);
  }
  for (size_t i = t0; i < 1536*512; i += st) {
    int k = (int)(i >> 9), n = (int)(i & 511);
    Wo1T[(size_t)n*1536 + k] = f2bf(W_o1[i]);
  }
  for (size_t i = t0; i < 600*512; i += st) {
    int row = (int)(i >> 9), jj = (int)(i & 511);
    int a = row / 300, sk = row % 300;
    Xtab[i] = f2bf(skill_embed[(size_t)sk*512 + jj] + ans_embed[(size_t)a*512 + jj]);
  }
  for (size_t i = t0; i < 300*512; i += st) PROt[i] = f2bf(skill_embed[i]);
  for (size_t i = t0; i < 16*32*512; i += st) ASG[i] = f2bf(ls_state[i & 511]);
  for (size_t i = t0; i < 512*512; i += st) {
    size_t b = i >> 9, n = i & 511;
    SKB[((size_t)b*199)*512 + n] = f2bf(skill_state0[n]);
  }
  for (size_t i = t0; i < 512*199; i += st) d_out[i] = 0.f;
  for (size_t i = t0; i < 16*32; i += st) BARp[i] = 0;
  (void)LAG;
}

// GAP / CAF precompute
__global__ void rekt_gap(const float* __restrict__ time_embed,
                         const float* __restrict__ W_sf, const float* __restrict__ b_sf,
                         const float* __restrict__ W_af, const float* __restrict__ b_af,
                         char* __restrict__ ws) {
  float* GAP = (float*)(ws + OFF_GAP);
  float* CAF = (float*)(ws + OFF_CAF);
  const int n = threadIdx.x;
  __shared__ float te[512];
  if (blockIdx.x < 200) {
    const int t = blockIdx.x;
    te[n] = time_embed[(size_t)t*512 + n];
    __syncthreads();
    float acc = b_sf[n];
    for (int k = 0; k < 512; ++k) acc = fmaf(te[k], W_sf[(size_t)(512 + k)*512 + n], acc);
    GAP[(size_t)t*512 + n] = acc;
  } else {
    te[n] = time_embed[512 + n];
    __syncthreads();
    float acc = b_af[n];
    for (int k = 0; k < 512; ++k) acc = fmaf(te[k], W_af[(size_t)(512 + k)*512 + n], acc);
    CAF[n] = acc;
  }
}

// ---------------- group barrier (8 blocks), agent scope ----------------
__device__ __forceinline__ void gbar(int* cnt, int target) {
  __syncthreads();
  if (threadIdx.x == 0) {
    __threadfence();
    __hip_atomic_fetch_add(cnt, 1, __ATOMIC_RELEASE, __HIP_MEMORY_SCOPE_AGENT);
    while (__hip_atomic_load(cnt, __ATOMIC_ACQUIRE, __HIP_MEMORY_SCOPE_AGENT) < target) {
      __builtin_amdgcn_s_sleep(2);
    }
    __threadfence();
  }
  __syncthreads();
}

// ---------------- main scan ----------------
// grid = 128 blocks: block (g,j) = 8g+j.  g = batch-group (32 batches), j = N-slice (64 cols).
// 512 threads = 8 waves: wave w -> m-half (w>>2), 16-col tile (w&3).
__global__ __launch_bounds__(512, 1) void rekt_main(
    const int* __restrict__ next_skill, const int* __restrict__ next_ans,
    const float* __restrict__ ls_state,
    const float* __restrict__ b_o1, const float* __restrict__ w_o2,
    const float* __restrict__ b_as, const float* __restrict__ b_ss,
    float* __restrict__ d_out, char* __restrict__ ws) {

  const ushort_t* WsfT = (const ushort_t*)(ws + OFF_WSFT);
  const ushort_t* WafT = (const ushort_t*)(ws + OFF_WAFT);
  const ushort_t* WasT = (const ushort_t*)(ws + OFF_WAST);
  const ushort_t* WssT = (const ushort_t*)(ws + OFF_WSST);
  const ushort_t* Wo1T = (const ushort_t*)(ws + OFF_WO1T);
  const ushort_t* Xtab = (const ushort_t*)(ws + OFF_XTAB);
  const ushort_t* PROt = (const ushort_t*)(ws + OFF_PRO);
  const float*    GAP  = (const float*)(ws + OFF_GAP);
  const float*    CAF  = (const float*)(ws + OFF_CAF);
  ushort_t* LAG = (ushort_t*)(ws + OFF_LAG);
  ushort_t* LSG = (ushort_t*)(ws + OFF_LSG);
  ushort_t* ASG = (ushort_t*)(ws + OFF_ASG);
  int*      BARp = (int*)(ws + OFF_BAR);
  ushort_t* SKB = (ushort_t*)(ws + OFF_SKB);

  // LDS: 4 tiles [32 rows][512 shorts], granule-XOR-swizzled (granule g at g^(r&7))
  __shared__ __align__(16) short T0[32*512];
  __shared__ __align__(16) short T1[32*512];
  __shared__ __align__(16) short T2[32*512];
  __shared__ __align__(16) short T3[32*512];
  __shared__ unsigned char LT[32*300];
  __shared__ int sk_s[32], gap_s[32], xr_s[32], skrow_s[32];

  const int tid = threadIdx.x;
  const int lane = tid & 63, w = tid >> 6;
  const int cc = lane & 15, hi = lane >> 4;
  const int rq = hi << 2;
  const int mh = w >> 2, nt = w & 3;
  const int g = blockIdx.x >> 3, j = blockIdx.x & 7;
  const int b0 = g << 5;
  const int ncol = j * 64 + nt * 16 + cc;      // this lane's output column
  const int arow = mh * 16 + cc;               // A-fragment row in tile
  const int r0 = mh * 16 + rq;                 // output row base (4 rows)
  int* cnt = BARp + g * 32;

  const float bo1 = b_o1[ncol];
  const float wo2 = w_o2[ncol];
  const float caf = CAF[ncol];
  const float bas = b_as[ncol];
  const float bss = b_ss[ncol];

  f32x4 as;
  {
    const float v = ls_state[ncol];
    as = (f32x4){v, v, v, v};
  }

  for (int i = tid; i < 32 * 300; i += 512) LT[i] = 0;
  __syncthreads();

  const ushort_t* bsf = WsfT + (size_t)ncol * 512 + hi * 8;
  const ushort_t* baf = WafT + (size_t)ncol * 512 + hi * 8;
  const ushort_t* wo1 = Wo1T + (size_t)ncol * 1536 + hi * 8;
  const ushort_t* was = WasT + (size_t)ncol * 1024 + hi * 8;
  const ushort_t* wss = WssT + (size_t)ncol * 1024 + hi * 8;
  const int aswz = ((cc & 7) << 3);            // A-read swizzle (row = arow, arow&7 == cc&7)

  int it = 0;
  for (int s = 0; s < 199; ++s) {
    // ---- indices (block-local, LT replicated per block) ----
    if (tid < 32) {
      const int b = b0 + tid;
      const int sk = next_skill[b * 199 + s];
      const int tl = (int)LT[tid * 300 + sk];
      sk_s[tid] = sk;
      gap_s[tid] = s - tl;
      xr_s[tid] = next_ans[b * 199 + s] * 300 + sk;
      skrow_s[tid] = b * 199 + tl;
      LT[tid * 300 + sk] = (unsigned char)s;
      }
    __syncthreads();

    // ---- stage phase A: T0 = SKg (gather), T1 = AS ----
    for (int i = tid; i < 2048; i += 512) {
      const int r = i >> 6, gi = i & 63;
      const int dst = r * 512 + ((gi ^ (r & 7)) << 3);
      *reinterpret_cast<uint4v*>(T0 + dst) =
          __builtin_nontemporal_load(reinterpret_cast<const uint4v*>(SKB + (size_t)skrow_s[r] * 512 + gi * 8));
      *reinterpret_cast<uint4v*>(T1 + dst) =
          __builtin_nontemporal_load(reinterpret_cast<const uint4v*>(ASG + (size_t)(g * 32 + r) * 512 + gi * 8));
    }
    __syncthreads();

    // ---- phase A GEMMs (2 chains) ----
    f32x4 fa = {0.f,0.f,0.f,0.f}, ga = {0.f,0.f,0.f,0.f};
    {
      const short* a0 = T0 + arow * 512;
      const short* a1 = T1 + arow * 512;
#pragma unroll 4
      for (int kk = 0; kk < 512; kk += 32) {
        const int go = ((((kk >> 3) + hi) << 3) ^ aswz);
        const short8 x0 = *reinterpret_cast<const short8*>(a0 + go);
        const short8 x1 = *reinterpret_cast<const short8*>(a1 + go);
        fa = __builtin_amdgcn_mfma_f32_16x16x32_bf16(x0, *reinterpret_cast<const short8*>(bsf + kk), fa, 0,0,0);
        ga = __builtin_amdgcn_mfma_f32_16x16x32_bf16(x1, *reinterpret_cast<const short8*>(baf + kk), ga, 0,0,0);
      }
    }

    // ---- epilogue A ----
    f32x4 la, ls;
#pragma unroll
    for (int q = 0; q < 4; ++q) {
      const int r = r0 + q;
      const float F = fa[q] + GAP[(size_t)gap_s[r] * 512 + ncol];
      const float sgF = 1.f / (1.f + __expf(-F));
      const float skg = bf2f((ushort_t)T0[r * 512 + (((ncol >> 3) ^ (r & 7)) << 3) + (ncol & 7)]);
      const float lsv = skg * sgF;
      ls[q] = lsv;
      __builtin_nontemporal_store(f2bf(lsv), LSG + (size_t)(g * 32 + r) * 512 + ncol);
      const float G = ga[q] + caf;
      const float sgG = 1.f / (1.f + __expf(-G));
      const float lav = as[q] * sgG;
      la[q] = lav;
      __builtin_nontemporal_store(f2bf(lav), LAG + (size_t)(g * 32 + r) * 512 + ncol);
    }
    gbar(cnt, 8 * (++it));

    // ---- stage phase B: T0=LA, T1=LS, T2=X, T3=PRO ----
    for (int i = tid; i < 2048; i += 512) {
      const int r = i >> 6, gi = i & 63;
      const int dst = r * 512 + ((gi ^ (r & 7)) << 3);
      *reinterpret_cast<uint4v*>(T0 + dst) =
          __builtin_nontemporal_load(reinterpret_cast<const uint4v*>(LAG + (size_t)(g * 32 + r) * 512 + gi * 8));
      *reinterpret_cast<uint4v*>(T1 + dst) =
          __builtin_nontemporal_load(reinterpret_cast<const uint4v*>(LSG + (size_t)(g * 32 + r) * 512 + gi * 8));
      *reinterpret_cast<uint4v*>(T2 + dst) =
          *reinterpret_cast<const uint4v*>(Xtab + (size_t)xr_s[r] * 512 + gi * 8);
      *reinterpret_cast<uint4v*>(T3 + dst) =
          *reinterpret_cast<const uint4v*>(PROt + (size_t)sk_s[r] * 512 + gi * 8);
    }
    __syncthreads();

    // ---- phase B GEMMs (7 chains) ----
    f32x4 h0 = {0.f,0.f,0.f,0.f}, h1 = h0, h2 = h0, na0 = h0, na1 = h0, ns0 = h0, ns1 = h0;
    {
      const short* aLA = T0 + arow * 512;
      const short* aLS = T1 + arow * 512;
      const short* aX  = T2 + arow * 512;
      const short* aP  = T3 + arow * 512;
#pragma unroll 2
      for (int kk = 0; kk < 512; kk += 32) {
        const int go = ((((kk >> 3) + hi) << 3) ^ aswz);
        const short8 xla = *reinterpret_cast<const short8*>(aLA + go);
        const short8 xls = *reinterpret_cast<const short8*>(aLS + go);
        const short8 xx  = *reinterpret_cast<const short8*>(aX + go);
        const short8 xp  = *reinterpret_cast<const short8*>(aP + go);
        h0  = __builtin_amdgcn_mfma_f32_16x16x32_bf16(xla, *reinterpret_cast<const short8*>(wo1 + kk),        h0, 0,0,0);
        h1  = __builtin_amdgcn_mfma_f32_16x16x32_bf16(xls, *reinterpret_cast<const short8*>(wo1 + 512 + kk),  h1, 0,0,0);
        h2  = __builtin_amdgcn_mfma_f32_16x16x32_bf16(xp,  *reinterpret_cast<const short8*>(wo1 + 1024 + kk), h2, 0,0,0);
        na0 = __builtin_amdgcn_mfma_f32_16x16x32_bf16(xla, *reinterpret_cast<const short8*>(was + kk),        na0, 0,0,0);
        na1 = __builtin_amdgcn_mfma_f32_16x16x32_bf16(xx,  *reinterpret_cast<const short8*>(was + 512 + kk),  na1, 0,0,0);
        ns0 = __builtin_amdgcn_mfma_f32_16x16x32_bf16(xls, *reinterpret_cast<const short8*>(wss + kk),        ns0, 0,0,0);
        ns1 = __builtin_amdgcn_mfma_f32_16x16x32_bf16(xx,  *reinterpret_cast<const short8*>(wss + 512 + kk),  ns1, 0,0,0);
      }
    }

    // ---- epilogue B ----
    float pv[4];
#pragma unroll
    for (int q = 0; q < 4; ++q) {
      const float h = fmaxf(h0[q] + h1[q] + h2[q] + bo1, 0.f);
      pv[q] = h * wo2;
    }
#pragma unroll
    for (int msk = 1; msk < 16; msk <<= 1) {
#pragma unroll
      for (int q = 0; q < 4; ++q) pv[q] += __shfl_xor(pv[q], msk, 64);
    }
    if (cc == 0) {
#pragma unroll
      for (int q = 0; q < 4; ++q) atomicAdd(&d_out[(size_t)(b0 + r0 + q) * 199 + s], pv[q]);
    }

#pragma unroll
    for (int q = 0; q < 4; ++q) {
      const int r = r0 + q;
      float x = na0[q] + na1[q] + bas;
      x = fminf(fmaxf(x, -12.f), 12.f);
      float e = __expf(2.f * x);
      const float nav = la[q] + (e - 1.f) / (e + 1.f);
      as[q] = nav;
      __builtin_nontemporal_store(f2bf(nav), ASG + (size_t)(g * 32 + r) * 512 + ncol);

      float y = ns0[q] + ns1[q] + bss;
      y = fminf(fmaxf(y, -12.f), 12.f);
      e = __expf(2.f * y);
      const float nsv = ls[q] + (e - 1.f) / (e + 1.f);
      __builtin_nontemporal_store(f2bf(nsv), SKB + ((size_t)(b0 + r) * 199 + s) * 512 + ncol);
    }
    gbar(cnt, 8 * (++it));
  }
}

// ---------------- tail: out = sigmoid(out + b_o2) ----------------
__global__ void rekt_out(float* __restrict__ d_out, const float* __restrict__ b_o2) {
  const int i = blockIdx.x * blockDim.x + threadIdx.x;
  if (i < 512 * 199) {
    const float v = d_out[i] + b_o2[0];
    d_out[i] = 1.f / (1.f + __expf(-v));
  }
}

extern "C" void kernel_launch(void* const* d_in, const int* in_sizes, int n_in,
                              void* d_out, int out_size, void* d_ws, size_t ws_size,
                              hipStream_t stream) {
  const int*   next_skill   = (const int*)d_in[4];
  const int*   next_ans     = (const int*)d_in[5];
  const float* skill_embed  = (const float*)d_in[6];
  const float* ans_embed    = (const float*)d_in[7];
  const float* time_embed   = (const float*)d_in[8];
  const float* ls_state     = (const float*)d_in[9];
  const float* skill_state0 = (const float*)d_in[10];
  const float* W_sf = (const float*)d_in[11];
  const float* b_sf = (const float*)d_in[12];
  const float* W_af = (const float*)d_in[13];
  const float* b_af = (const float*)d_in[14];
  const float* W_ss = (const float*)d_in[15];
  const float* b_ss = (const float*)d_in[16];
  const float* W_as = (const float*)d_in[17];
  const float* b_as = (const float*)d_in[18];
  const float* W_o1 = (const float*)d_in[19];
  const float* b_o1 = (const float*)d_in[20];
  const float* W_o2 = (const float*)d_in[21];
  const float* b_o2 = (const float*)d_in[22];
  float* out = (float*)d_out;
  char*  ws  = (char*)d_ws;

  if (ws_size < WS_NEED) return;

  rekt_prep<<<dim3(1024), dim3(256), 0, stream>>>(
      skill_embed, ans_embed, ls_state, skill_state0,
      W_sf, W_af, W_ss, W_as, W_o1, out, ws);
  rekt_gap<<<dim3(201), dim3(512), 0, stream>>>(time_embed, W_sf, b_sf, W_af, b_af, ws);

  rekt_main<<<dim3(128), dim3(512), 0, stream>>>(
      next_skill, next_ans, ls_state, b_o1, W_o2, b_as, b_ss, out, ws);

  rekt_out<<<dim3((512 * 199 + 255) / 256), dim3(256), 0, stream>>>(out, b_o2);
}

// Round 4
// 10451.938 us; speedup vs baseline: 2.4987x; 1.2463x over previous
//
#include <hip/hip_runtime.h>

typedef unsigned short ushort_t;
typedef unsigned int uint_t;
typedef __attribute__((ext_vector_type(8))) short short8;
typedef __attribute__((ext_vector_type(4))) float f32x4;
typedef __attribute__((ext_vector_type(4))) uint_t uint4v;

// ---------------- workspace layout (bytes) ----------------
constexpr size_t OFF_WSFT = 0;                               // bf16 [512][512]  WsfT[n][k]=W_sf[k][n]
constexpr size_t OFF_WAFT = OFF_WSFT + 512*512*2;            // bf16 [512][512]
constexpr size_t OFF_WAST = OFF_WAFT + 512*512*2;            // bf16 [512][1024]
constexpr size_t OFF_WSST = OFF_WAST + 512*1024*2;           // bf16 [512][1024]
constexpr size_t OFF_WO1T = OFF_WSST + 512*1024*2;           // bf16 [512][1536]
constexpr size_t OFF_XTAB = OFF_WO1T + 512*1536*2;           // bf16 [600][512]
constexpr size_t OFF_PRO  = OFF_XTAB + 600*512*2;            // bf16 [300][512]
constexpr size_t OFF_GAP  = OFF_PRO  + 300*512*2;            // f32  [200][512]
constexpr size_t OFF_CAF  = OFF_GAP  + 200*512*4;            // f32  [512]
constexpr size_t OFF_LAG  = OFF_CAF  + 512*4;                // bf16 [512][512] gated last_all (exchange, L3)
constexpr size_t OFF_LSG  = OFF_LAG  + 512*512*2;            // bf16 [512][512] gated last_sk
constexpr size_t OFF_ASG  = OFF_LSG  + 512*512*2;            // bf16 [512][512] all_state
constexpr size_t OFF_BAR  = OFF_ASG  + 512*512*2;            // i32  [16][32] barrier counters
constexpr size_t OFF_SKB  = OFF_BAR  + 16*32*4;              // bf16 [512][199][512] skill_buf
constexpr size_t WS_NEED  = OFF_SKB  + (size_t)512*199*512*2;

__device__ __forceinline__ ushort_t f2bf(float f) {
  union { float f; uint_t u; } v; v.f = f;
  uint_t u = v.u;
  return (ushort_t)((u + 0x7FFFu + ((u >> 16) & 1u)) >> 16);
}
__device__ __forceinline__ float bf2f(ushort_t h) {
  union { uint_t u; float f; } v; v.u = ((uint_t)h) << 16;
  return v.f;
}

// relaxed agent-scope (sc0 sc1) coherent access — no fences, L3 is the meet point
__device__ __forceinline__ uint_t coh_ld(const void* p) {
  return __hip_atomic_load((const uint_t*)p, __ATOMIC_RELAXED, __HIP_MEMORY_SCOPE_AGENT);
}
__device__ __forceinline__ void coh_st(void* p, uint_t v) {
  __hip_atomic_store((uint_t*)p, v, __ATOMIC_RELAXED, __HIP_MEMORY_SCOPE_AGENT);
}

// ---------------- prologue ----------------
__global__ void rekt_prep(const float* __restrict__ skill_embed, const float* __restrict__ ans_embed,
                          const float* __restrict__ ls_state, const float* __restrict__ skill_state0,
                          const float* __restrict__ W_sf, const float* __restrict__ W_af,
                          const float* __restrict__ W_ss, const float* __restrict__ W_as,
                          const float* __restrict__ W_o1,
                          float* __restrict__ d_out, char* __restrict__ ws) {
  ushort_t* WsfT = (ushort_t*)(ws + OFF_WSFT);
  ushort_t* WafT = (ushort_t*)(ws + OFF_WAFT);
  ushort_t* WasT = (ushort_t*)(ws + OFF_WAST);
  ushort_t* WssT = (ushort_t*)(ws + OFF_WSST);
  ushort_t* Wo1T = (ushort_t*)(ws + OFF_WO1T);
  ushort_t* Xtab = (ushort_t*)(ws + OFF_XTAB);
  ushort_t* PROt = (ushort_t*)(ws + OFF_PRO);
  ushort_t* ASG  = (ushort_t*)(ws + OFF_ASG);
  int*      BARp = (int*)(ws + OFF_BAR);
  ushort_t* SKB  = (ushort_t*)(ws + OFF_SKB);

  const size_t t0 = (size_t)blockIdx.x * blockDim.x + threadIdx.x;
  const size_t st = (size_t)gridDim.x * blockDim.x;

  for (size_t i = t0; i < 512*512; i += st) {
    int k = (int)(i >> 9), n = (int)(i & 511);
    WsfT[(size_t)n*512 + k] = f2bf(W_sf[i]);
    WafT[(size_t)n*512 + k] = f2bf(W_af[i]);
  }
  for (size_t i = t0; i < 1024*512; i += st) {
    int k = (int)(i >> 9), n = (int)(i & 511);
    WasT[(size_t)n*1024 + k] = f2bf(W_as[i]);
    WssT[(size_t)n*1024 + k] = f2bf(W_ss[i]);
  }
  for (size_t i = t0; i < 1536*512; i += st) {
    int k = (int)(i >> 9), n = (int)(i & 511);
    Wo1T[(size_t)n*1536 + k] = f2bf(W_o1[i]);
  }
  for (size_t i = t0; i < 600*512; i += st) {
    int row = (int)(i >> 9), jj = (int)(i & 511);
    int a = row / 300, sk = row % 300;
    Xtab[i] = f2bf(skill_embed[(size_t)sk*512 + jj] + ans_embed[(size_t)a*512 + jj]);
  }
  for (size_t i = t0; i < 300*512; i += st) PROt[i] = f2bf(skill_embed[i]);
  for (size_t i = t0; i < 512*512; i += st) ASG[i] = f2bf(ls_state[i & 511]);
  for (size_t i = t0; i < 512*512; i += st) {
    size_t b = i >> 9, n = i & 511;
    SKB[((size_t)b*199)*512 + n] = f2bf(skill_state0[n]);
  }
  for (size_t i = t0; i < 512*199; i += st) d_out[i] = 0.f;
  for (size_t i = t0; i < 16*32; i += st) BARp[i] = 0;
}

// GAP / CAF precompute
__global__ void rekt_gap(const float* __restrict__ time_embed,
                         const float* __restrict__ W_sf, const float* __restrict__ b_sf,
                         const float* __restrict__ W_af, const float* __restrict__ b_af,
                         char* __restrict__ ws) {
  float* GAP = (float*)(ws + OFF_GAP);
  float* CAF = (float*)(ws + OFF_CAF);
  const int n = threadIdx.x;
  __shared__ float te[512];
  if (blockIdx.x < 200) {
    const int t = blockIdx.x;
    te[n] = time_embed[(size_t)t*512 + n];
    __syncthreads();
    float acc = b_sf[n];
    for (int k = 0; k < 512; ++k) acc = fmaf(te[k], W_sf[(size_t)(512 + k)*512 + n], acc);
    GAP[(size_t)t*512 + n] = acc;
  } else {
    te[n] = time_embed[512 + n];
    __syncthreads();
    float acc = b_af[n];
    for (int k = 0; k < 512; ++k) acc = fmaf(te[k], W_af[(size_t)(512 + k)*512 + n], acc);
    CAF[n] = acc;
  }
}

// ---------------- fence-free group barrier (8 blocks) ----------------
// __syncthreads drains vmcnt (sc1 stores acked at L3 = coherence point); RMW+spin relaxed.
__device__ __forceinline__ void gbar(int* cnt, int target) {
  __syncthreads();
  if (threadIdx.x == 0) {
    __hip_atomic_fetch_add(cnt, 1, __ATOMIC_RELAXED, __HIP_MEMORY_SCOPE_AGENT);
    while (__hip_atomic_load(cnt, __ATOMIC_RELAXED, __HIP_MEMORY_SCOPE_AGENT) < target) {
      __builtin_amdgcn_s_sleep(2);
    }
  }
  __syncthreads();
}

// ---------------- main scan ----------------
// grid = 128 blocks: block (g,j) = 8g+j.  g = batch-group (32 batches), j = N-slice (64 cols) -> XCD j.
// 512 threads = 8 waves: wave w -> m-half (w>>2), 16-col tile (w&3).
__global__ __launch_bounds__(512, 1) void rekt_main(
    const int* __restrict__ next_skill, const int* __restrict__ next_ans,
    const float* __restrict__ ls_state,
    const float* __restrict__ b_o1, const float* __restrict__ w_o2,
    const float* __restrict__ b_as, const float* __restrict__ b_ss,
    float* __restrict__ d_out, char* __restrict__ ws) {

  const ushort_t* WsfT = (const ushort_t*)(ws + OFF_WSFT);
  const ushort_t* WafT = (const ushort_t*)(ws + OFF_WAFT);
  const ushort_t* WasT = (const ushort_t*)(ws + OFF_WAST);
  const ushort_t* WssT = (const ushort_t*)(ws + OFF_WSST);
  const ushort_t* Wo1T = (const ushort_t*)(ws + OFF_WO1T);
  const ushort_t* Xtab = (const ushort_t*)(ws + OFF_XTAB);
  const ushort_t* PROt = (const ushort_t*)(ws + OFF_PRO);
  const float*    GAP  = (const float*)(ws + OFF_GAP);
  const float*    CAF  = (const float*)(ws + OFF_CAF);
  ushort_t* LAG = (ushort_t*)(ws + OFF_LAG);
  ushort_t* LSG = (ushort_t*)(ws + OFF_LSG);
  ushort_t* ASG = (ushort_t*)(ws + OFF_ASG);
  int*      BARp = (int*)(ws + OFF_BAR);
  ushort_t* SKB = (ushort_t*)(ws + OFF_SKB);

  // LDS: 4 tiles [32 rows][512 shorts], granule-XOR swizzle (granule gi stored at gi^(r&7))
  __shared__ __align__(16) short T0[32*512];
  __shared__ __align__(16) short T1[32*512];
  __shared__ __align__(16) short T2[32*512];
  __shared__ __align__(16) short T3[32*512];
  __shared__ unsigned char LT[32*300];
  __shared__ int sk_s[32], gap_s[32], xr_s[32], skrow_s[32];

  const int tid = threadIdx.x;
  const int lane = tid & 63, w = tid >> 6;
  const int cc = lane & 15, hi = lane >> 4;
  const int rq = hi << 2;
  const int mh = w >> 2, nt = w & 3;
  const int g = blockIdx.x >> 3, j = blockIdx.x & 7;
  const int b0 = g << 5;
  const int ncol = j * 64 + nt * 16 + cc;
  const int arow = mh * 16 + cc;
  const int r0 = mh * 16 + rq;
  int* cnt = BARp + g * 32;

  const float bo1 = b_o1[ncol];
  const float wo2 = w_o2[ncol];
  const float caf = CAF[ncol];
  const float bas = b_as[ncol];
  const float bss = b_ss[ncol];

  f32x4 as;
  {
    const float v = ls_state[ncol];
    as = (f32x4){v, v, v, v};
  }

  for (int i = tid; i < 32 * 300; i += 512) LT[i] = 0;
  __syncthreads();

  const ushort_t* bsf = WsfT + (size_t)ncol * 512 + hi * 8;
  const ushort_t* baf = WafT + (size_t)ncol * 512 + hi * 8;
  const ushort_t* wo1 = Wo1T + (size_t)ncol * 1536 + hi * 8;
  const ushort_t* was = WasT + (size_t)ncol * 1024 + hi * 8;
  const ushort_t* wss = WssT + (size_t)ncol * 1024 + hi * 8;
  const int aswz = ((cc & 7) << 3);

  int it = 0;
  for (int s = 0; s < 199; ++s) {
    if (tid < 32) {
      const int b = b0 + tid;
      const int sk = next_skill[b * 199 + s];
      const int tl = (int)LT[tid * 300 + sk];
      sk_s[tid] = sk;
      gap_s[tid] = s - tl;
      xr_s[tid] = next_ans[b * 199 + s] * 300 + sk;
      skrow_s[tid] = b * 199 + tl;
      LT[tid * 300 + sk] = (unsigned char)s;
    }
    __syncthreads();

    // ---- stage: T0=SKg (coherent gather), T1=AS (coherent), T2=X, T3=PRO (cached) ----
#pragma unroll 4
    for (int t = 0; t < 16; ++t) {
      const int flat = (t << 9) + tid;
      const int r = flat >> 8, u = flat & 255;          // u: uint index in row (256 per row)
      const int gi = u >> 2, e = u & 3;
      const int dsts = r * 512 + (((gi ^ (r & 7)) << 3) | (e << 1));
      const uint_t va = coh_ld((const uint_t*)(SKB + (size_t)skrow_s[r] * 512) + u);
      *reinterpret_cast<uint_t*>(T0 + dsts) = va;
      const uint_t vb = coh_ld((const uint_t*)(ASG + (size_t)(b0 + r) * 512) + u);
      *reinterpret_cast<uint_t*>(T1 + dsts) = vb;
    }
    for (int i = tid; i < 2048; i += 512) {
      const int r = i >> 6, gi = i & 63;
      const int dst = r * 512 + ((gi ^ (r & 7)) << 3);
      *reinterpret_cast<uint4v*>(T2 + dst) =
          *reinterpret_cast<const uint4v*>(Xtab + (size_t)xr_s[r] * 512 + gi * 8);
      *reinterpret_cast<uint4v*>(T3 + dst) =
          *reinterpret_cast<const uint4v*>(PROt + (size_t)sk_s[r] * 512 + gi * 8);
    }
    __syncthreads();

    // ---- phase A GEMMs ----
    f32x4 fa = {0.f,0.f,0.f,0.f}, ga = {0.f,0.f,0.f,0.f};
    {
      const short* a0 = T0 + arow * 512;
      const short* a1 = T1 + arow * 512;
#pragma unroll 4
      for (int kk = 0; kk < 512; kk += 32) {
        const int go = ((((kk >> 3) + hi) << 3) ^ aswz);
        const short8 x0 = *reinterpret_cast<const short8*>(a0 + go);
        const short8 x1 = *reinterpret_cast<const short8*>(a1 + go);
        fa = __builtin_amdgcn_mfma_f32_16x16x32_bf16(x0, *reinterpret_cast<const short8*>(bsf + kk), fa, 0,0,0);
        ga = __builtin_amdgcn_mfma_f32_16x16x32_bf16(x1, *reinterpret_cast<const short8*>(baf + kk), ga, 0,0,0);
      }
    }

    // ---- epilogue A: LS = SKg*sig(F), LA = AS*sig(G); coherent-store packed pairs ----
    f32x4 la, ls;
    uint_t pa[4], ps[4];
#pragma unroll
    for (int q = 0; q < 4; ++q) {
      const int r = r0 + q;
      const float F = fa[q] + GAP[(size_t)gap_s[r] * 512 + ncol];
      const float sgF = 1.f / (1.f + __expf(-F));
      const float skg = bf2f((ushort_t)T0[r * 512 + (((ncol >> 3) ^ (r & 7)) << 3) + (ncol & 7)]);
      const float lsv = skg * sgF;
      ls[q] = lsv;
      ps[q] = f2bf(lsv);
      const float G = ga[q] + caf;
      const float sgG = 1.f / (1.f + __expf(-G));
      const float lav = as[q] * sgG;
      la[q] = lav;
      pa[q] = f2bf(lav);
    }
    {
      const bool even = (cc & 1) == 0;
      const int ucol = ncol >> 1;
#pragma unroll
      for (int q = 0; q < 4; ++q) {
        const int r = b0 + r0 + q;
        const uint_t oa = (uint_t)__shfl_xor((int)pa[q], 1, 64);
        const uint_t os = (uint_t)__shfl_xor((int)ps[q], 1, 64);
        if (even) {
          coh_st((uint_t*)(LAG + (size_t)r * 512) + ucol, pa[q] | (oa << 16));
          coh_st((uint_t*)(LSG + (size_t)r * 512) + ucol, ps[q] | (os << 16));
        }
      }
    }
    gbar(cnt, 8 * (++it));

    // ---- restage: T0=LA, T1=LS (coherent) ----
#pragma unroll 4
    for (int t = 0; t < 16; ++t) {
      const int flat = (t << 9) + tid;
      const int r = flat >> 8, u = flat & 255;
      const int gi = u >> 2, e = u & 3;
      const int dsts = r * 512 + (((gi ^ (r & 7)) << 3) | (e << 1));
      const uint_t va = coh_ld((const uint_t*)(LAG + (size_t)(b0 + r) * 512) + u);
      *reinterpret_cast<uint_t*>(T0 + dsts) = va;
      const uint_t vb = coh_ld((const uint_t*)(LSG + (size_t)(b0 + r) * 512) + u);
      *reinterpret_cast<uint_t*>(T1 + dsts) = vb;
    }
    __syncthreads();

    // ---- phase B GEMMs (7 chains) ----
    f32x4 h0 = {0.f,0.f,0.f,0.f}, h1 = h0, h2 = h0, na0 = h0, na1 = h0, ns0 = h0, ns1 = h0;
    {
      const short* aLA = T0 + arow * 512;
      const short* aLS = T1 + arow * 512;
      const short* aX  = T2 + arow * 512;
      const short* aP  = T3 + arow * 512;
#pragma unroll 2
      for (int kk = 0; kk < 512; kk += 32) {
        const int go = ((((kk >> 3) + hi) << 3) ^ aswz);
        const short8 xla = *reinterpret_cast<const short8*>(aLA + go);
        const short8 xls = *reinterpret_cast<const short8*>(aLS + go);
        const short8 xx  = *reinterpret_cast<const short8*>(aX + go);
        const short8 xp  = *reinterpret_cast<const short8*>(aP + go);
        h0  = __builtin_amdgcn_mfma_f32_16x16x32_bf16(xla, *reinterpret_cast<const short8*>(wo1 + kk),        h0, 0,0,0);
        h1  = __builtin_amdgcn_mfma_f32_16x16x32_bf16(xls, *reinterpret_cast<const short8*>(wo1 + 512 + kk),  h1, 0,0,0);
        h2  = __builtin_amdgcn_mfma_f32_16x16x32_bf16(xp,  *reinterpret_cast<const short8*>(wo1 + 1024 + kk), h2, 0,0,0);
        na0 = __builtin_amdgcn_mfma_f32_16x16x32_bf16(xla, *reinterpret_cast<const short8*>(was + kk),        na0, 0,0,0);
        na1 = __builtin_amdgcn_mfma_f32_16x16x32_bf16(xx,  *reinterpret_cast<const short8*>(was + 512 + kk),  na1, 0,0,0);
        ns0 = __builtin_amdgcn_mfma_f32_16x16x32_bf16(xls, *reinterpret_cast<const short8*>(wss + kk),        ns0, 0,0,0);
        ns1 = __builtin_amdgcn_mfma_f32_16x16x32_bf16(xx,  *reinterpret_cast<const short8*>(wss + 512 + kk),  ns1, 0,0,0);
      }
    }

    // ---- epilogue B ----
    float pv[4];
#pragma unroll
    for (int q = 0; q < 4; ++q) {
      const float h = fmaxf(h0[q] + h1[q] + h2[q] + bo1, 0.f);
      pv[q] = h * wo2;
    }
#pragma unroll
    for (int msk = 1; msk < 16; msk <<= 1) {
#pragma unroll
      for (int q = 0; q < 4; ++q) pv[q] += __shfl_xor(pv[q], msk, 64);
    }
    if (cc == 0) {
#pragma unroll
      for (int q = 0; q < 4; ++q) atomicAdd(&d_out[(size_t)(b0 + r0 + q) * 199 + s], pv[q]);
    }

    uint_t qa[4], qs[4];
#pragma unroll
    for (int q = 0; q < 4; ++q) {
      float x = na0[q] + na1[q] + bas;
      x = fminf(fmaxf(x, -12.f), 12.f);
      float e = __expf(2.f * x);
      const float nav = la[q] + (e - 1.f) / (e + 1.f);
      as[q] = nav;
      qa[q] = f2bf(nav);

      float y = ns0[q] + ns1[q] + bss;
      y = fminf(fmaxf(y, -12.f), 12.f);
      e = __expf(2.f * y);
      const float nsv = ls[q] + (e - 1.f) / (e + 1.f);
      qs[q] = f2bf(nsv);
    }
    {
      const bool even = (cc & 1) == 0;
      const int ucol = ncol >> 1;
#pragma unroll
      for (int q = 0; q < 4; ++q) {
        const int r = b0 + r0 + q;
        const uint_t oa = (uint_t)__shfl_xor((int)qa[q], 1, 64);
        const uint_t os = (uint_t)__shfl_xor((int)qs[q], 1, 64);
        if (even) {
          coh_st((uint_t*)(ASG + (size_t)r * 512) + ucol, qa[q] | (oa << 16));
          coh_st((uint_t*)(SKB + ((size_t)r * 199 + s) * 512) + ucol, qs[q] | (os << 16));
        }
      }
    }
    gbar(cnt, 8 * (++it));
  }
}

// ---------------- tail: out = sigmoid(out + b_o2) ----------------
__global__ void rekt_out(float* __restrict__ d_out, const float* __restrict__ b_o2) {
  const int i = blockIdx.x * blockDim.x + threadIdx.x;
  if (i < 512 * 199) {
    const float v = d_out[i] + b_o2[0];
    d_out[i] = 1.f / (1.f + __expf(-v));
  }
}

extern "C" void kernel_launch(void* const* d_in, const int* in_sizes, int n_in,
                              void* d_out, int out_size, void* d_ws, size_t ws_size,
                              hipStream_t stream) {
  const int*   next_skill   = (const int*)d_in[4];
  const int*   next_ans     = (const int*)d_in[5];
  const float* skill_embed  = (const float*)d_in[6];
  const float* ans_embed    = (const float*)d_in[7];
  const float* time_embed   = (const float*)d_in[8];
  const float* ls_state     = (const float*)d_in[9];
  const float* skill_state0 = (const float*)d_in[10];
  const float* W_sf = (const float*)d_in[11];
  const float* b_sf = (const float*)d_in[12];
  const float* W_af = (const float*)d_in[13];
  const float* b_af = (const float*)d_in[14];
  const float* W_ss = (const float*)d_in[15];
  const float* b_ss = (const float*)d_in[16];
  const float* W_as = (const float*)d_in[17];
  const float* b_as = (const float*)d_in[18];
  const float* W_o1 = (const float*)d_in[19];
  const float* b_o1 = (const float*)d_in[20];
  const float* W_o2 = (const float*)d_in[21];
  const float* b_o2 = (const float*)d_in[22];
  float* out = (float*)d_out;
  char*  ws  = (char*)d_ws;

  if (ws_size < WS_NEED) return;

  rekt_prep<<<dim3(1024), dim3(256), 0, stream>>>(
      skill_embed, ans_embed, ls_state, skill_state0,
      W_sf, W_af, W_ss, W_as, W_o1, out, ws);
  rekt_gap<<<dim3(201), dim3(512), 0, stream>>>(time_embed, W_sf, b_sf, W_af, b_af, ws);

  rekt_main<<<dim3(128), dim3(512), 0, stream>>>(
      next_skill, next_ans, ls_state, b_o1, W_o2, b_as, b_ss, out, ws);

  rekt_out<<<dim3((512 * 199 + 255) / 256), dim3(256), 0, stream>>>(out, b_o2);
}